// Round 8
// baseline (245.678 us; speedup 1.0000x reference)
//
#include <hip/hip_runtime.h>
#include <hip/hip_fp16.h>
#include <math.h>

#define BB 4
#define CC 128
#define HF 128
#define WF 128
#define GATHER_NB 2048   // 8 groups x 256 blocks

typedef float f4 __attribute__((ext_vector_type(4)));
typedef unsigned int u2 __attribute__((ext_vector_type(2)));

// ---------- helpers with fp-contract OFF to bit-match the numpy reference ----------
__device__ __forceinline__ float wsum3(float a, float wa, float b, float wb, float c, float wc) {
#pragma clang fp contract(off)
    {
        float r = a * wa;
        r = r + b * wb;
        r = r + c * wc;
        return r;
    }
}

__device__ __forceinline__ float to_pix(float cv, int Wm1, int WFm1) {
#pragma clang fp contract(off)
    {
        float g = cv / (float)Wm1 * 2.0f - 1.0f;
        return (g + 1.0f) * 0.5f * (float)WFm1;
    }
}

// ---------- 1. NCHW -> NHWC transpose of feature_map, fused with depth init ----------
__global__ void transpose_fm(const float* __restrict__ fm, float* __restrict__ fmT,
                             float* __restrict__ depth) {
    __shared__ float tile[32][33];
    int b = blockIdx.z;
    int hw0 = blockIdx.x * 32;
    int c0 = blockIdx.y * 32;
    int tx = threadIdx.x;
    int ty = threadIdx.y;
    // fused depth-buffer init: 8192 blocks x 256 threads cover the 1,048,576 texels
    int gid = (((blockIdx.z * gridDim.y + blockIdx.y) * gridDim.x + blockIdx.x) << 8) +
              (ty << 5) + tx;
    if (gid < BB * 512 * 512) depth[gid] = INFINITY;
    const float* in = fm + (size_t)b * CC * HF * WF;
    float* out = fmT + (size_t)b * HF * WF * CC;
    #pragma unroll
    for (int i = ty; i < 32; i += 8)
        tile[i][tx] = in[(size_t)(c0 + i) * (HF * WF) + hw0 + tx];
    __syncthreads();
    #pragma unroll
    for (int i = ty; i < 32; i += 8)
        out[(size_t)(hw0 + i) * CC + c0 + tx] = tile[tx][i];
}

// ---------- 2. scatter-min of vertex depths ----------
__global__ void depth_scatter(const float* __restrict__ v2d, const float* __restrict__ v3d,
                              float* __restrict__ depth, int Nv, const int* pH, const int* pW) {
    int H = *pH, W = *pW;
    int i = blockIdx.x * blockDim.x + threadIdx.x;
    if (i >= BB * Nv) return;
    int b = i / Nv, v = i - b * Nv;
    float x = v2d[((size_t)b * Nv + v) * 2 + 0];
    float y = v2d[((size_t)b * Nv + v) * 2 + 1];
    int xv = (int)rintf(x);
    int yv = (int)rintf(y);
    if (xv < 0 || xv >= W || yv < 0 || yv >= H) return;
    float z = v3d[((size_t)b * Nv + v) * 3 + 2];
    // z > 0 always, inf init: int compare == float compare for non-negative floats
    atomicMin((int*)&depth[(size_t)b * H * W + (size_t)yv * W + xv], __float_as_int(z));
}

// ---------- 3. per-point setup: writes vw, c3, and COMPACT 8B params (all NT) ----------
__global__ void __launch_bounds__(256)
point_setup(const float* __restrict__ v2d, const float* __restrict__ v3d,
            const int* __restrict__ parents, const float* __restrict__ bary,
            const float* __restrict__ depth,
            float* __restrict__ out_vw, float* __restrict__ out_c3,
            u2* __restrict__ params,
            int N, int Nv, int K, const int* pH, const int* pW) {
    int H = *pH, W = *pW;
    int idx = blockIdx.x * blockDim.x + threadIdx.x;
    if (idx >= BB * N) return;
    int b = idx / N, n = idx - b * N;
    int k = n % K;
    float w0 = bary[k * 3 + 0], w1 = bary[k * 3 + 1], w2 = bary[k * 3 + 2];
    int i0 = parents[(size_t)n * 3 + 0];
    int i1 = parents[(size_t)n * 3 + 1];
    int i2 = parents[(size_t)n * 3 + 2];
    const float* v2b = v2d + (size_t)b * Nv * 2;
    const float* v3b = v3d + (size_t)b * Nv * 3;
    float ax = v2b[(size_t)i0 * 2], ay = v2b[(size_t)i0 * 2 + 1];
    float bx = v2b[(size_t)i1 * 2], by = v2b[(size_t)i1 * 2 + 1];
    float cx = v2b[(size_t)i2 * 2], cy = v2b[(size_t)i2 * 2 + 1];
    float c2x = wsum3(ax, w0, bx, w1, cx, w2);
    float c2y = wsum3(ay, w0, by, w1, cy, w2);
    float a0 = v3b[(size_t)i0 * 3], a1 = v3b[(size_t)i0 * 3 + 1], a2 = v3b[(size_t)i0 * 3 + 2];
    float b0 = v3b[(size_t)i1 * 3], b1 = v3b[(size_t)i1 * 3 + 1], b2 = v3b[(size_t)i1 * 3 + 2];
    float c0 = v3b[(size_t)i2 * 3], c1 = v3b[(size_t)i2 * 3 + 1], c2 = v3b[(size_t)i2 * 3 + 2];
    float c3x = wsum3(a0, w0, b0, w1, c0, w2);
    float c3y = wsum3(a1, w0, b1, w1, c1, w2);
    float c3z = wsum3(a2, w0, b2, w1, c2, w2);
    float e1x = b0 - a0, e1y = b1 - a1, e1z = b2 - a2;
    float e2x = c0 - a0, e2y = c1 - a1, e2z = c2 - a2;
    float nx = e1y * e2z - e1z * e2y;
    float ny = e1z * e2x - e1x * e2z;
    float nz = e1x * e2y - e1y * e2x;
    float nn = sqrtf(nx * nx + ny * ny + nz * nz) + 1e-8f;
    nx /= nn; ny /= nn; nz /= nn;
    float vn = sqrtf(c3x * c3x + c3y * c3y + c3z * c3z) + 1e-8f;
    float vx = -c3x / vn, vy = -c3y / vn, vz = -c3z / vn;
    float ang = fmaxf(nx * vx + ny * vy + nz * vz, 0.0f);
    int xc = (int)rintf(c2x); xc = min(max(xc, 0), W - 1);
    int yc = (int)rintf(c2y); yc = min(max(yc, 0), H - 1);
    float dsamp = depth[(size_t)b * H * W + (size_t)yc * W + xc];
    bool visible = (c3z <= dsamp + 1e-3f) || isinf(dsamp);
    __builtin_nontemporal_store(visible ? ang : 0.0f, &out_vw[idx]);
    __builtin_nontemporal_store(c3x, &out_c3[(size_t)idx * 3 + 0]);
    __builtin_nontemporal_store(c3y, &out_c3[(size_t)idx * 3 + 1]);
    __builtin_nontemporal_store(c3z, &out_c3[(size_t)idx * 3 + 2]);
    float px = to_pix(c2x, W - 1, WF - 1);
    float py = to_pix(c2y, H - 1, HF - 1);
    float x0f = floorf(px), y0f = floorf(py);
    int x0i = (int)x0f, y0i = (int)y0f;
    float wx = px - x0f, wy = py - y0f;
    unsigned int xs = (unsigned int)min(max(x0i + 8, 0), 65535);
    unsigned int ys = (unsigned int)min(max(y0i + 8, 0), 65535);
    unsigned short hx = __half_as_ushort(__float2half(wx));
    unsigned short hy = __half_as_ushort(__float2half(wy));
    u2 rec;
    rec.x = (ys << 16) | xs;
    rec.y = ((unsigned int)hy << 16) | hx;
    __builtin_nontemporal_store(rec, &params[idx]);
}

// ---------- 4. channel-split gather: slab-only L2 footprint, NT param loads ----------
// 8 groups = (batch, channel-half); group = blockIdx & 7 pins each group to one XCD.
// Cacheable working set per XCD = its 4 MB half-slab exactly; params NT-loaded.
__global__ void __launch_bounds__(256)
gather_feats(const float* __restrict__ fmT, const u2* __restrict__ params,
             float* __restrict__ out, int N) {
    int group = blockIdx.x & 7;       // -> XCD
    int off = blockIdx.x >> 3;        // 0..255 within group
    int b = group >> 1;               // batch
    int h = group & 1;                // channel half
    int span = (N + 255) >> 8;        // points per block
    int start = off * span;
    int end = min(start + span, N);
    int lane = threadIdx.x & 15;      // 16 lanes x 4 ch = 64 channels
    int slot = threadIdx.x >> 4;      // 16 point-slots per block
    int co = h * 64 + lane * 4;
    const float* base = fmT + (size_t)b * HF * WF * CC;
    const u2* pbase = params + (size_t)b * N;
    f4* obase = (f4*)out + (size_t)b * N * (CC / 4);
    for (int n = start + slot; n < end; n += 16) {
        u2 rec = __builtin_nontemporal_load(&pbase[n]);
        int x0 = (int)(rec.x & 0xffff) - 8;
        int y0 = (int)(rec.x >> 16) - 8;
        float wx = __half2float(__ushort_as_half((unsigned short)(rec.y & 0xffff)));
        float wy = __half2float(__ushort_as_half((unsigned short)(rec.y >> 16)));
        // clamped indices + zeroed weights (matches reference clip + w*ok exactly)
        int xA = min(max(x0, 0), WF - 1), xB = min(max(x0 + 1, 0), WF - 1);
        int yA = min(max(y0, 0), HF - 1), yB = min(max(y0 + 1, 0), HF - 1);
        float okxA = (x0 >= 0 && x0 < WF) ? 1.0f : 0.0f;
        float okxB = (x0 + 1 >= 0 && x0 + 1 < WF) ? 1.0f : 0.0f;
        float okyA = (y0 >= 0 && y0 < HF) ? 1.0f : 0.0f;
        float okyB = (y0 + 1 >= 0 && y0 + 1 < HF) ? 1.0f : 0.0f;
        float w00 = (1.0f - wx) * (1.0f - wy) * okxA * okyA;
        float w10 = wx * (1.0f - wy) * okxB * okyA;
        float w01 = (1.0f - wx) * wy * okxA * okyB;
        float w11 = wx * wy * okxB * okyB;
        const f4* p00 = (const f4*)(base + ((size_t)yA * WF + xA) * CC + co);
        const f4* p10 = (const f4*)(base + ((size_t)yA * WF + xB) * CC + co);
        const f4* p01 = (const f4*)(base + ((size_t)yB * WF + xA) * CC + co);
        const f4* p11 = (const f4*)(base + ((size_t)yB * WF + xB) * CC + co);
        f4 v00 = *p00, v10 = *p10, v01 = *p01, v11 = *p11;
        f4 acc = v00 * w00 + v10 * w10 + v01 * w01 + v11 * w11;
        __builtin_nontemporal_store(acc, obase + (size_t)n * (CC / 4) + h * 16 + lane);
    }
}

extern "C" void kernel_launch(void* const* d_in, const int* in_sizes, int n_in,
                              void* d_out, int out_size, void* d_ws, size_t ws_size,
                              hipStream_t stream) {
    const float* fm = (const float*)d_in[0];
    const float* v2d = (const float*)d_in[1];
    const float* v3d = (const float*)d_in[2];
    const int* parents = (const int*)d_in[3];
    const float* bary = (const float*)d_in[4];
    const int* pH = (const int*)d_in[5];
    const int* pW = (const int*)d_in[6];

    int Nv = in_sizes[1] / (BB * 2);
    int N = in_sizes[3] / 3;
    int K = in_sizes[4] / 3;

    // workspace layout (floats): fmT | depth | params(u2)
    float* fmT = (float*)d_ws;
    float* depth = fmT + (size_t)BB * CC * HF * WF;            // +8,388,608
    u2* params = (u2*)(depth + (size_t)BB * 512 * 512);        // 800,000 x 8B

    float* out_lf = (float*)d_out;
    float* out_vw = out_lf + (size_t)BB * N * CC;
    float* out_c3 = out_vw + (size_t)BB * N;

    hipLaunchKernelGGL(transpose_fm, dim3(HF * WF / 32, CC / 32, BB), dim3(32, 8), 0, stream,
                       fm, fmT, depth);
    hipLaunchKernelGGL(depth_scatter, dim3((BB * Nv + 255) / 256), dim3(256), 0, stream,
                       v2d, v3d, depth, Nv, pH, pW);
    hipLaunchKernelGGL(point_setup, dim3((BB * N + 255) / 256), dim3(256), 0, stream,
                       v2d, v3d, parents, bary, depth, out_vw, out_c3, params,
                       N, Nv, K, pH, pW);
    hipLaunchKernelGGL(gather_feats, dim3(GATHER_NB), dim3(256), 0, stream,
                       fmT, (const u2*)params, out_lf, N);
}

// Round 9
// 128.180 us; speedup vs baseline: 1.9167x; 1.9167x over previous
//
#include <hip/hip_runtime.h>
#include <hip/hip_fp16.h>
#include <math.h>

#define BB 4
#define CC 128
#define HF 128
#define WF 128
#define GATHER_NB 2048   // 8 groups x 256 blocks

typedef float f4 __attribute__((ext_vector_type(4)));
typedef unsigned int u2 __attribute__((ext_vector_type(2)));

// ---------- helpers with fp-contract OFF to bit-match the numpy reference ----------
__device__ __forceinline__ float wsum3(float a, float wa, float b, float wb, float c, float wc) {
#pragma clang fp contract(off)
    {
        float r = a * wa;
        r = r + b * wb;
        r = r + c * wc;
        return r;
    }
}

__device__ __forceinline__ float to_pix(float cv, int Wm1, int WFm1) {
#pragma clang fp contract(off)
    {
        float g = cv / (float)Wm1 * 2.0f - 1.0f;
        return (g + 1.0f) * 0.5f * (float)WFm1;
    }
}

__device__ __forceinline__ unsigned short f32_bf16_rne(float f) {
    unsigned int u = __float_as_uint(f);
    unsigned int r = u + 0x7fffu + ((u >> 16) & 1u);
    return (unsigned short)(r >> 16);
}

// ---------- 1. NCHW -> NHWC bf16 transpose of feature_map, fused with depth init ----------
__global__ void transpose_fm(const float* __restrict__ fm, unsigned short* __restrict__ fmT,
                             float* __restrict__ depth) {
    __shared__ float tile[32][33];
    int b = blockIdx.z;
    int hw0 = blockIdx.x * 32;
    int c0 = blockIdx.y * 32;
    int tx = threadIdx.x;
    int ty = threadIdx.y;
    // fused depth-buffer init: 8192 blocks x 256 threads cover the 1,048,576 texels
    int gid = (((blockIdx.z * gridDim.y + blockIdx.y) * gridDim.x + blockIdx.x) << 8) +
              (ty << 5) + tx;
    if (gid < BB * 512 * 512) depth[gid] = INFINITY;
    const float* in = fm + (size_t)b * CC * HF * WF;
    unsigned short* out = fmT + (size_t)b * HF * WF * CC;
    #pragma unroll
    for (int i = ty; i < 32; i += 8)
        tile[i][tx] = in[(size_t)(c0 + i) * (HF * WF) + hw0 + tx];
    __syncthreads();
    #pragma unroll
    for (int i = ty; i < 32; i += 8)
        out[(size_t)(hw0 + i) * CC + c0 + tx] = f32_bf16_rne(tile[tx][i]);
}

// ---------- 2. scatter-min of vertex depths ----------
__global__ void depth_scatter(const float* __restrict__ v2d, const float* __restrict__ v3d,
                              float* __restrict__ depth, int Nv, const int* pH, const int* pW) {
    int H = *pH, W = *pW;
    int i = blockIdx.x * blockDim.x + threadIdx.x;
    if (i >= BB * Nv) return;
    int b = i / Nv, v = i - b * Nv;
    float x = v2d[((size_t)b * Nv + v) * 2 + 0];
    float y = v2d[((size_t)b * Nv + v) * 2 + 1];
    int xv = (int)rintf(x);
    int yv = (int)rintf(y);
    if (xv < 0 || xv >= W || yv < 0 || yv >= H) return;
    float z = v3d[((size_t)b * Nv + v) * 3 + 2];
    // z > 0 always, inf init: int compare == float compare for non-negative floats
    atomicMin((int*)&depth[(size_t)b * H * W + (size_t)yv * W + xv], __float_as_int(z));
}

// ---------- 3. per-point setup: vw, c3 (regular stores), compact 8B params ----------
__global__ void __launch_bounds__(256)
point_setup(const float* __restrict__ v2d, const float* __restrict__ v3d,
            const int* __restrict__ parents, const float* __restrict__ bary,
            const float* __restrict__ depth,
            float* __restrict__ out_vw, float* __restrict__ out_c3,
            u2* __restrict__ params,
            int N, int Nv, int K, const int* pH, const int* pW) {
    int H = *pH, W = *pW;
    int idx = blockIdx.x * blockDim.x + threadIdx.x;
    if (idx >= BB * N) return;
    int b = idx / N, n = idx - b * N;
    int k = n % K;
    float w0 = bary[k * 3 + 0], w1 = bary[k * 3 + 1], w2 = bary[k * 3 + 2];
    int i0 = parents[(size_t)n * 3 + 0];
    int i1 = parents[(size_t)n * 3 + 1];
    int i2 = parents[(size_t)n * 3 + 2];
    const float* v2b = v2d + (size_t)b * Nv * 2;
    const float* v3b = v3d + (size_t)b * Nv * 3;
    float ax = v2b[(size_t)i0 * 2], ay = v2b[(size_t)i0 * 2 + 1];
    float bx = v2b[(size_t)i1 * 2], by = v2b[(size_t)i1 * 2 + 1];
    float cx = v2b[(size_t)i2 * 2], cy = v2b[(size_t)i2 * 2 + 1];
    float c2x = wsum3(ax, w0, bx, w1, cx, w2);
    float c2y = wsum3(ay, w0, by, w1, cy, w2);
    float a0 = v3b[(size_t)i0 * 3], a1 = v3b[(size_t)i0 * 3 + 1], a2 = v3b[(size_t)i0 * 3 + 2];
    float b0 = v3b[(size_t)i1 * 3], b1 = v3b[(size_t)i1 * 3 + 1], b2 = v3b[(size_t)i1 * 3 + 2];
    float c0 = v3b[(size_t)i2 * 3], c1 = v3b[(size_t)i2 * 3 + 1], c2 = v3b[(size_t)i2 * 3 + 2];
    float c3x = wsum3(a0, w0, b0, w1, c0, w2);
    float c3y = wsum3(a1, w0, b1, w1, c1, w2);
    float c3z = wsum3(a2, w0, b2, w1, c2, w2);
    float e1x = b0 - a0, e1y = b1 - a1, e1z = b2 - a2;
    float e2x = c0 - a0, e2y = c1 - a1, e2z = c2 - a2;
    float nx = e1y * e2z - e1z * e2y;
    float ny = e1z * e2x - e1x * e2z;
    float nz = e1x * e2y - e1y * e2x;
    float nn = sqrtf(nx * nx + ny * ny + nz * nz) + 1e-8f;
    nx /= nn; ny /= nn; nz /= nn;
    float vn = sqrtf(c3x * c3x + c3y * c3y + c3z * c3z) + 1e-8f;
    float vx = -c3x / vn, vy = -c3y / vn, vz = -c3z / vn;
    float ang = fmaxf(nx * vx + ny * vy + nz * vz, 0.0f);
    int xc = (int)rintf(c2x); xc = min(max(xc, 0), W - 1);
    int yc = (int)rintf(c2y); yc = min(max(yc, 0), H - 1);
    float dsamp = depth[(size_t)b * H * W + (size_t)yc * W + xc];
    bool visible = (c3z <= dsamp + 1e-3f) || isinf(dsamp);
    out_vw[idx] = visible ? ang : 0.0f;
    out_c3[(size_t)idx * 3 + 0] = c3x;
    out_c3[(size_t)idx * 3 + 1] = c3y;
    out_c3[(size_t)idx * 3 + 2] = c3z;
    float px = to_pix(c2x, W - 1, WF - 1);
    float py = to_pix(c2y, H - 1, HF - 1);
    float x0f = floorf(px), y0f = floorf(py);
    int x0i = (int)x0f, y0i = (int)y0f;
    float wx = px - x0f, wy = py - y0f;
    unsigned int xs = (unsigned int)min(max(x0i + 8, 0), 65535);
    unsigned int ys = (unsigned int)min(max(y0i + 8, 0), 65535);
    unsigned short hx = __half_as_ushort(__float2half(wx));
    unsigned short hy = __half_as_ushort(__float2half(wy));
    u2 rec;
    rec.x = (ys << 16) | xs;
    rec.y = ((unsigned int)hy << 16) | hx;
    params[idx] = rec;
}

// ---------- 4. channel-split gather over bf16 slab: 2MB/XCD L2-resident ----------
// 8 groups = (batch, channel-half); group = blockIdx & 7 pins each group to one XCD.
__global__ void __launch_bounds__(256)
gather_feats(const unsigned short* __restrict__ fmT, const u2* __restrict__ params,
             float* __restrict__ out, int N) {
    int group = blockIdx.x & 7;       // -> XCD
    int off = blockIdx.x >> 3;        // 0..255 within group
    int b = group >> 1;               // batch
    int h = group & 1;                // channel half
    int span = (N + 255) >> 8;        // points per block
    int start = off * span;
    int end = min(start + span, N);
    int lane = threadIdx.x & 15;      // 16 lanes x 4 ch = 64 channels
    int slot = threadIdx.x >> 4;      // 16 point-slots per block
    int co = h * 64 + lane * 4;
    const unsigned short* base = fmT + (size_t)b * HF * WF * CC;
    const u2* pbase = params + (size_t)b * N;
    f4* obase = (f4*)out + (size_t)b * N * (CC / 4);
    for (int n = start + slot; n < end; n += 16) {
        u2 rec = pbase[n];
        int x0 = (int)(rec.x & 0xffff) - 8;
        int y0 = (int)(rec.x >> 16) - 8;
        float wx = __half2float(__ushort_as_half((unsigned short)(rec.y & 0xffff)));
        float wy = __half2float(__ushort_as_half((unsigned short)(rec.y >> 16)));
        // clamped indices + zeroed weights (matches reference clip + w*ok exactly)
        int xA = min(max(x0, 0), WF - 1), xB = min(max(x0 + 1, 0), WF - 1);
        int yA = min(max(y0, 0), HF - 1), yB = min(max(y0 + 1, 0), HF - 1);
        float okxA = (x0 >= 0 && x0 < WF) ? 1.0f : 0.0f;
        float okxB = (x0 + 1 >= 0 && x0 + 1 < WF) ? 1.0f : 0.0f;
        float okyA = (y0 >= 0 && y0 < HF) ? 1.0f : 0.0f;
        float okyB = (y0 + 1 >= 0 && y0 + 1 < HF) ? 1.0f : 0.0f;
        float w00 = (1.0f - wx) * (1.0f - wy) * okxA * okyA;
        float w10 = wx * (1.0f - wy) * okxB * okyA;
        float w01 = (1.0f - wx) * wy * okxA * okyB;
        float w11 = wx * wy * okxB * okyB;
        const u2* q00 = (const u2*)(base + ((size_t)yA * WF + xA) * CC + co);
        const u2* q10 = (const u2*)(base + ((size_t)yA * WF + xB) * CC + co);
        const u2* q01 = (const u2*)(base + ((size_t)yB * WF + xA) * CC + co);
        const u2* q11 = (const u2*)(base + ((size_t)yB * WF + xB) * CC + co);
        u2 r00 = *q00, r10 = *q10, r01 = *q01, r11 = *q11;
#define BF16X4(r, v)                                                \
        f4 v;                                                       \
        v.x = __uint_as_float((r.x & 0xffffu) << 16);               \
        v.y = __uint_as_float(r.x & 0xffff0000u);                   \
        v.z = __uint_as_float((r.y & 0xffffu) << 16);               \
        v.w = __uint_as_float(r.y & 0xffff0000u);
        BF16X4(r00, v00); BF16X4(r10, v10); BF16X4(r01, v01); BF16X4(r11, v11);
#undef BF16X4
        f4 acc = v00 * w00 + v10 * w10 + v01 * w01 + v11 * w11;
        __builtin_nontemporal_store(acc, obase + (size_t)n * (CC / 4) + h * 16 + lane);
    }
}

extern "C" void kernel_launch(void* const* d_in, const int* in_sizes, int n_in,
                              void* d_out, int out_size, void* d_ws, size_t ws_size,
                              hipStream_t stream) {
    const float* fm = (const float*)d_in[0];
    const float* v2d = (const float*)d_in[1];
    const float* v3d = (const float*)d_in[2];
    const int* parents = (const int*)d_in[3];
    const float* bary = (const float*)d_in[4];
    const int* pH = (const int*)d_in[5];
    const int* pW = (const int*)d_in[6];

    int Nv = in_sizes[1] / (BB * 2);
    int N = in_sizes[3] / 3;
    int K = in_sizes[4] / 3;

    // workspace layout: fmT bf16 (16.8MB) | depth (4MB) | params (6.4MB)
    unsigned short* fmT = (unsigned short*)d_ws;
    float* depth = (float*)(fmT + (size_t)BB * HF * WF * CC);
    u2* params = (u2*)(depth + (size_t)BB * 512 * 512);

    float* out_lf = (float*)d_out;
    float* out_vw = out_lf + (size_t)BB * N * CC;
    float* out_c3 = out_vw + (size_t)BB * N;

    hipLaunchKernelGGL(transpose_fm, dim3(HF * WF / 32, CC / 32, BB), dim3(32, 8), 0, stream,
                       fm, fmT, depth);
    hipLaunchKernelGGL(depth_scatter, dim3((BB * Nv + 255) / 256), dim3(256), 0, stream,
                       v2d, v3d, depth, Nv, pH, pW);
    hipLaunchKernelGGL(point_setup, dim3((BB * N + 255) / 256), dim3(256), 0, stream,
                       v2d, v3d, parents, bary, depth, out_vw, out_c3, params,
                       N, Nv, K, pH, pW);
    hipLaunchKernelGGL(gather_feats, dim3(GATHER_NB), dim3(256), 0, stream,
                       fmT, (const u2*)params, out_lf, N);
}

// Round 10
// 125.151 us; speedup vs baseline: 1.9631x; 1.0242x over previous
//
#include <hip/hip_runtime.h>
#include <hip/hip_fp16.h>
#include <math.h>

#define BB 4
#define CC 128
#define HF 128
#define WF 128
#define GATHER_NB 2048   // 8 groups x 256 blocks

typedef float f4 __attribute__((ext_vector_type(4)));
typedef unsigned int u2 __attribute__((ext_vector_type(2)));

// ---------- helpers with fp-contract OFF to bit-match the numpy reference ----------
__device__ __forceinline__ float wsum3(float a, float wa, float b, float wb, float c, float wc) {
#pragma clang fp contract(off)
    {
        float r = a * wa;
        r = r + b * wb;
        r = r + c * wc;
        return r;
    }
}

__device__ __forceinline__ float to_pix(float cv, int Wm1, int WFm1) {
#pragma clang fp contract(off)
    {
        float g = cv / (float)Wm1 * 2.0f - 1.0f;
        return (g + 1.0f) * 0.5f * (float)WFm1;
    }
}

__device__ __forceinline__ unsigned short f32_bf16_rne(float f) {
    unsigned int u = __float_as_uint(f);
    unsigned int r = u + 0x7fffu + ((u >> 16) & 1u);
    return (unsigned short)(r >> 16);
}

// ---------- 1. NCHW -> NHWC bf16 transpose of feature_map, fused with depth init ----------
__global__ void transpose_fm(const float* __restrict__ fm, unsigned short* __restrict__ fmT,
                             float* __restrict__ depth) {
    __shared__ float tile[32][33];
    int b = blockIdx.z;
    int hw0 = blockIdx.x * 32;
    int c0 = blockIdx.y * 32;
    int tx = threadIdx.x;
    int ty = threadIdx.y;
    // fused depth-buffer init: 8192 blocks x 256 threads cover the 1,048,576 texels
    int gid = (((blockIdx.z * gridDim.y + blockIdx.y) * gridDim.x + blockIdx.x) << 8) +
              (ty << 5) + tx;
    if (gid < BB * 512 * 512) depth[gid] = INFINITY;
    const float* in = fm + (size_t)b * CC * HF * WF;
    unsigned short* out = fmT + (size_t)b * HF * WF * CC;
    #pragma unroll
    for (int i = ty; i < 32; i += 8)
        tile[i][tx] = in[(size_t)(c0 + i) * (HF * WF) + hw0 + tx];
    __syncthreads();
    #pragma unroll
    for (int i = ty; i < 32; i += 8)
        out[(size_t)(hw0 + i) * CC + c0 + tx] = f32_bf16_rne(tile[tx][i]);
}

// ---------- 2. scatter-min of vertex depths ----------
__global__ void depth_scatter(const float* __restrict__ v2d, const float* __restrict__ v3d,
                              float* __restrict__ depth, int Nv, const int* pH, const int* pW) {
    int H = *pH, W = *pW;
    int i = blockIdx.x * blockDim.x + threadIdx.x;
    if (i >= BB * Nv) return;
    int b = i / Nv, v = i - b * Nv;
    float x = v2d[((size_t)b * Nv + v) * 2 + 0];
    float y = v2d[((size_t)b * Nv + v) * 2 + 1];
    int xv = (int)rintf(x);
    int yv = (int)rintf(y);
    if (xv < 0 || xv >= W || yv < 0 || yv >= H) return;
    float z = v3d[((size_t)b * Nv + v) * 3 + 2];
    // z > 0 always, inf init: int compare == float compare for non-negative floats
    atomicMin((int*)&depth[(size_t)b * H * W + (size_t)yv * W + xv], __float_as_int(z));
}

// ---------- 3. fused setup + channel-split gather ----------
// 8 groups = (batch, channel-half); group = blockIdx & 7 pins each group to one XCD.
// Per 256-point tile: phase 1 = each thread does one point's setup -> params in LDS
// (h==0 groups also write vw/c3); phase 2 = 16 slots x 16 lanes bilinear gather.
__global__ void __launch_bounds__(256)
gather_fused(const unsigned short* __restrict__ fmT,
             const float* __restrict__ v2d, const float* __restrict__ v3d,
             const int* __restrict__ parents, const float* __restrict__ bary,
             const float* __restrict__ depth,
             float* __restrict__ out_vw, float* __restrict__ out_c3,
             float* __restrict__ out, int N, int Nv, int K,
             const int* pH, const int* pW) {
    __shared__ u2 sp[256];
    int tid = threadIdx.x;
    int group = blockIdx.x & 7;       // -> XCD
    int off = blockIdx.x >> 3;        // 0..255 within group
    int b = group >> 1;               // batch
    int h = group & 1;                // channel half
    int span = (N + 255) >> 8;        // points per block
    int start = off * span;
    int end = min(start + span, N);
    int H = *pH, W = *pW;
    int lane = tid & 15;              // 16 lanes x 4 ch = 64 channels
    int slot = tid >> 4;              // 16 point-slots
    int co = h * 64 + lane * 4;
    const unsigned short* base = fmT + (size_t)b * HF * WF * CC;
    const float* v2b = v2d + (size_t)b * Nv * 2;
    const float* v3b = v3d + (size_t)b * Nv * 3;
    const float* dep = depth + (size_t)b * H * W;
    f4* obase = (f4*)out + (size_t)b * N * (CC / 4);

    for (int t0 = start; t0 < end; t0 += 256) {
        int cnt = min(end - t0, 256);
        // ---- phase 1: setup for 256 points ----
        if (tid < cnt) {
            int n = t0 + tid;
            int idx = b * N + n;
            int k = n % K;
            float w0 = bary[k * 3 + 0], w1 = bary[k * 3 + 1], w2 = bary[k * 3 + 2];
            int i0 = parents[(size_t)n * 3 + 0];
            int i1 = parents[(size_t)n * 3 + 1];
            int i2 = parents[(size_t)n * 3 + 2];
            float ax = v2b[(size_t)i0 * 2], ay = v2b[(size_t)i0 * 2 + 1];
            float bx = v2b[(size_t)i1 * 2], by = v2b[(size_t)i1 * 2 + 1];
            float cx = v2b[(size_t)i2 * 2], cy = v2b[(size_t)i2 * 2 + 1];
            float c2x = wsum3(ax, w0, bx, w1, cx, w2);
            float c2y = wsum3(ay, w0, by, w1, cy, w2);
            float a0 = v3b[(size_t)i0 * 3], a1 = v3b[(size_t)i0 * 3 + 1], a2 = v3b[(size_t)i0 * 3 + 2];
            float b0 = v3b[(size_t)i1 * 3], b1 = v3b[(size_t)i1 * 3 + 1], b2 = v3b[(size_t)i1 * 3 + 2];
            float c0 = v3b[(size_t)i2 * 3], c1 = v3b[(size_t)i2 * 3 + 1], c2 = v3b[(size_t)i2 * 3 + 2];
            float c3x = wsum3(a0, w0, b0, w1, c0, w2);
            float c3y = wsum3(a1, w0, b1, w1, c1, w2);
            float c3z = wsum3(a2, w0, b2, w1, c2, w2);
            if (h == 0) {
                float e1x = b0 - a0, e1y = b1 - a1, e1z = b2 - a2;
                float e2x = c0 - a0, e2y = c1 - a1, e2z = c2 - a2;
                float nx = e1y * e2z - e1z * e2y;
                float ny = e1z * e2x - e1x * e2z;
                float nz = e1x * e2y - e1y * e2x;
                float nn = sqrtf(nx * nx + ny * ny + nz * nz) + 1e-8f;
                nx /= nn; ny /= nn; nz /= nn;
                float vn = sqrtf(c3x * c3x + c3y * c3y + c3z * c3z) + 1e-8f;
                float vx = -c3x / vn, vy = -c3y / vn, vz = -c3z / vn;
                float ang = fmaxf(nx * vx + ny * vy + nz * vz, 0.0f);
                int xc = (int)rintf(c2x); xc = min(max(xc, 0), W - 1);
                int yc = (int)rintf(c2y); yc = min(max(yc, 0), H - 1);
                float dsamp = dep[(size_t)yc * W + xc];
                bool visible = (c3z <= dsamp + 1e-3f) || isinf(dsamp);
                out_vw[idx] = visible ? ang : 0.0f;
                out_c3[(size_t)idx * 3 + 0] = c3x;
                out_c3[(size_t)idx * 3 + 1] = c3y;
                out_c3[(size_t)idx * 3 + 2] = c3z;
            }
            float px = to_pix(c2x, W - 1, WF - 1);
            float py = to_pix(c2y, H - 1, HF - 1);
            float x0f = floorf(px), y0f = floorf(py);
            int x0i = (int)x0f, y0i = (int)y0f;
            float wx = px - x0f, wy = py - y0f;
            unsigned int xs = (unsigned int)min(max(x0i + 8, 0), 65535);
            unsigned int ys = (unsigned int)min(max(y0i + 8, 0), 65535);
            unsigned short hx = __half_as_ushort(__float2half(wx));
            unsigned short hy = __half_as_ushort(__float2half(wy));
            u2 rec;
            rec.x = (ys << 16) | xs;
            rec.y = ((unsigned int)hy << 16) | hx;
            sp[tid] = rec;
        }
        __syncthreads();
        // ---- phase 2: gather 256 points, 16 slots x 16 lanes ----
        for (int i = slot; i < cnt; i += 16) {
            u2 rec = sp[i];   // slot-uniform -> LDS broadcast
            int n = t0 + i;
            int x0 = (int)(rec.x & 0xffff) - 8;
            int y0 = (int)(rec.x >> 16) - 8;
            float wx = __half2float(__ushort_as_half((unsigned short)(rec.y & 0xffff)));
            float wy = __half2float(__ushort_as_half((unsigned short)(rec.y >> 16)));
            // clamped indices + zeroed weights (matches reference clip + w*ok exactly)
            int xA = min(max(x0, 0), WF - 1), xB = min(max(x0 + 1, 0), WF - 1);
            int yA = min(max(y0, 0), HF - 1), yB = min(max(y0 + 1, 0), HF - 1);
            float okxA = (x0 >= 0 && x0 < WF) ? 1.0f : 0.0f;
            float okxB = (x0 + 1 >= 0 && x0 + 1 < WF) ? 1.0f : 0.0f;
            float okyA = (y0 >= 0 && y0 < HF) ? 1.0f : 0.0f;
            float okyB = (y0 + 1 >= 0 && y0 + 1 < HF) ? 1.0f : 0.0f;
            float w00 = (1.0f - wx) * (1.0f - wy) * okxA * okyA;
            float w10 = wx * (1.0f - wy) * okxB * okyA;
            float w01 = (1.0f - wx) * wy * okxA * okyB;
            float w11 = wx * wy * okxB * okyB;
            const u2* q00 = (const u2*)(base + ((size_t)yA * WF + xA) * CC + co);
            const u2* q10 = (const u2*)(base + ((size_t)yA * WF + xB) * CC + co);
            const u2* q01 = (const u2*)(base + ((size_t)yB * WF + xA) * CC + co);
            const u2* q11 = (const u2*)(base + ((size_t)yB * WF + xB) * CC + co);
            u2 r00 = *q00, r10 = *q10, r01 = *q01, r11 = *q11;
#define BF16X4(r, v)                                                \
            f4 v;                                                   \
            v.x = __uint_as_float((r.x & 0xffffu) << 16);           \
            v.y = __uint_as_float(r.x & 0xffff0000u);               \
            v.z = __uint_as_float((r.y & 0xffffu) << 16);           \
            v.w = __uint_as_float(r.y & 0xffff0000u);
            BF16X4(r00, v00); BF16X4(r10, v10); BF16X4(r01, v01); BF16X4(r11, v11);
#undef BF16X4
            f4 acc = v00 * w00 + v10 * w10 + v01 * w01 + v11 * w11;
            __builtin_nontemporal_store(acc, obase + (size_t)n * (CC / 4) + h * 16 + lane);
        }
        __syncthreads();
    }
}

extern "C" void kernel_launch(void* const* d_in, const int* in_sizes, int n_in,
                              void* d_out, int out_size, void* d_ws, size_t ws_size,
                              hipStream_t stream) {
    const float* fm = (const float*)d_in[0];
    const float* v2d = (const float*)d_in[1];
    const float* v3d = (const float*)d_in[2];
    const int* parents = (const int*)d_in[3];
    const float* bary = (const float*)d_in[4];
    const int* pH = (const int*)d_in[5];
    const int* pW = (const int*)d_in[6];

    int Nv = in_sizes[1] / (BB * 2);
    int N = in_sizes[3] / 3;
    int K = in_sizes[4] / 3;

    // workspace layout: fmT bf16 (16.8MB) | depth (4MB)
    unsigned short* fmT = (unsigned short*)d_ws;
    float* depth = (float*)(fmT + (size_t)BB * HF * WF * CC);

    float* out_lf = (float*)d_out;
    float* out_vw = out_lf + (size_t)BB * N * CC;
    float* out_c3 = out_vw + (size_t)BB * N;

    hipLaunchKernelGGL(transpose_fm, dim3(HF * WF / 32, CC / 32, BB), dim3(32, 8), 0, stream,
                       fm, fmT, depth);
    hipLaunchKernelGGL(depth_scatter, dim3((BB * Nv + 255) / 256), dim3(256), 0, stream,
                       v2d, v3d, depth, Nv, pH, pW);
    hipLaunchKernelGGL(gather_fused, dim3(GATHER_NB), dim3(256), 0, stream,
                       fmT, v2d, v3d, parents, bary, depth, out_vw, out_c3, out_lf,
                       N, Nv, K, pH, pW);
}

// Round 11
// 114.450 us; speedup vs baseline: 2.1466x; 1.0935x over previous
//
#include <hip/hip_runtime.h>
#include <hip/hip_fp16.h>
#include <math.h>

#define BB 4
#define CC 128
#define HF 128
#define WF 128
#define GATHER_NB 2048   // 8 groups x 256 blocks

typedef float f4 __attribute__((ext_vector_type(4)));
typedef unsigned int u2 __attribute__((ext_vector_type(2)));

// ---------- helpers with fp-contract OFF to bit-match the numpy reference ----------
__device__ __forceinline__ float wsum3(float a, float wa, float b, float wb, float c, float wc) {
#pragma clang fp contract(off)
    {
        float r = a * wa;
        r = r + b * wb;
        r = r + c * wc;
        return r;
    }
}

__device__ __forceinline__ float to_pix(float cv, int Wm1, int WFm1) {
#pragma clang fp contract(off)
    {
        float g = cv / (float)Wm1 * 2.0f - 1.0f;
        return (g + 1.0f) * 0.5f * (float)WFm1;
    }
}

__device__ __forceinline__ unsigned short f32_bf16_rne(float f) {
    unsigned int u = __float_as_uint(f);
    unsigned int r = u + 0x7fffu + ((u >> 16) & 1u);
    return (unsigned short)(r >> 16);
}

// ---------- 1. NCHW -> NHWC bf16 transpose of feature_map, fused with depth init ----------
__global__ void transpose_fm(const float* __restrict__ fm, unsigned short* __restrict__ fmT,
                             float* __restrict__ depth) {
    __shared__ float tile[32][33];
    int b = blockIdx.z;
    int hw0 = blockIdx.x * 32;
    int c0 = blockIdx.y * 32;
    int tx = threadIdx.x;
    int ty = threadIdx.y;
    // fused depth-buffer init: 8192 blocks x 256 threads cover the 1,048,576 texels
    int gid = (((blockIdx.z * gridDim.y + blockIdx.y) * gridDim.x + blockIdx.x) << 8) +
              (ty << 5) + tx;
    if (gid < BB * 512 * 512) depth[gid] = INFINITY;
    const float* in = fm + (size_t)b * CC * HF * WF;
    unsigned short* out = fmT + (size_t)b * HF * WF * CC;
    #pragma unroll
    for (int i = ty; i < 32; i += 8)
        tile[i][tx] = in[(size_t)(c0 + i) * (HF * WF) + hw0 + tx];
    __syncthreads();
    #pragma unroll
    for (int i = ty; i < 32; i += 8)
        out[(size_t)(hw0 + i) * CC + c0 + tx] = f32_bf16_rne(tile[tx][i]);
}

// ---------- 2. scatter-min of vertex depths ----------
__global__ void depth_scatter(const float* __restrict__ v2d, const float* __restrict__ v3d,
                              float* __restrict__ depth, int Nv, const int* pH, const int* pW) {
    int H = *pH, W = *pW;
    int i = blockIdx.x * blockDim.x + threadIdx.x;
    if (i >= BB * Nv) return;
    int b = i / Nv, v = i - b * Nv;
    float x = v2d[((size_t)b * Nv + v) * 2 + 0];
    float y = v2d[((size_t)b * Nv + v) * 2 + 1];
    int xv = (int)rintf(x);
    int yv = (int)rintf(y);
    if (xv < 0 || xv >= W || yv < 0 || yv >= H) return;
    float z = v3d[((size_t)b * Nv + v) * 3 + 2];
    // z > 0 always, inf init: int compare == float compare for non-negative floats
    atomicMin((int*)&depth[(size_t)b * H * W + (size_t)yv * W + xv], __float_as_int(z));
}

// ---------- 3. fused setup + gather; groups = (batch, point-half) ----------
// 8 groups, group = blockIdx & 7 -> one XCD each. Each group owns a CONTIGUOUS
// range of points with ALL 128 channels: a wave writes 2 consecutive full
// 512-B rows -> one sequential 51-MB NT write stream per XCD (fill pattern).
// Per 256-point tile: phase 1 = per-thread setup -> params in LDS (+vw/c3);
// phase 2 = 8 slots x 32 lanes bilinear gather.
__global__ void __launch_bounds__(256)
gather_fused(const unsigned short* __restrict__ fmT,
             const float* __restrict__ v2d, const float* __restrict__ v3d,
             const int* __restrict__ parents, const float* __restrict__ bary,
             const float* __restrict__ depth,
             float* __restrict__ out_vw, float* __restrict__ out_c3,
             float* __restrict__ out, int N, int Nv, int K,
             const int* pH, const int* pW) {
    __shared__ u2 sp[256];
    int tid = threadIdx.x;
    int group = blockIdx.x & 7;       // -> XCD
    int off = blockIdx.x >> 3;        // 0..255 within group
    int b = group >> 1;               // batch
    int p = group & 1;                // point half
    int half = (N + 1) >> 1;
    int gstart = p * half;
    int gend = min(gstart + half, N);
    int span = (gend - gstart + 255) >> 8;
    int start = gstart + off * span;
    int end = min(start + span, gend);
    int H = *pH, W = *pW;
    int lane = tid & 31;              // 32 lanes x 4 ch = 128 channels
    int slot = tid >> 5;              // 8 point-slots
    int co = lane * 4;
    const unsigned short* base = fmT + (size_t)b * HF * WF * CC;
    const float* v2b = v2d + (size_t)b * Nv * 2;
    const float* v3b = v3d + (size_t)b * Nv * 3;
    const float* dep = depth + (size_t)b * H * W;
    f4* obase = (f4*)out + (size_t)b * N * (CC / 4);

    for (int t0 = start; t0 < end; t0 += 256) {
        int cnt = min(end - t0, 256);
        // ---- phase 1: setup for 256 points ----
        if (tid < cnt) {
            int n = t0 + tid;
            int idx = b * N + n;
            int k = n % K;
            float w0 = bary[k * 3 + 0], w1 = bary[k * 3 + 1], w2 = bary[k * 3 + 2];
            int i0 = parents[(size_t)n * 3 + 0];
            int i1 = parents[(size_t)n * 3 + 1];
            int i2 = parents[(size_t)n * 3 + 2];
            float ax = v2b[(size_t)i0 * 2], ay = v2b[(size_t)i0 * 2 + 1];
            float bx = v2b[(size_t)i1 * 2], by = v2b[(size_t)i1 * 2 + 1];
            float cx = v2b[(size_t)i2 * 2], cy = v2b[(size_t)i2 * 2 + 1];
            float c2x = wsum3(ax, w0, bx, w1, cx, w2);
            float c2y = wsum3(ay, w0, by, w1, cy, w2);
            float a0 = v3b[(size_t)i0 * 3], a1 = v3b[(size_t)i0 * 3 + 1], a2 = v3b[(size_t)i0 * 3 + 2];
            float b0 = v3b[(size_t)i1 * 3], b1 = v3b[(size_t)i1 * 3 + 1], b2 = v3b[(size_t)i1 * 3 + 2];
            float c0 = v3b[(size_t)i2 * 3], c1 = v3b[(size_t)i2 * 3 + 1], c2 = v3b[(size_t)i2 * 3 + 2];
            float c3x = wsum3(a0, w0, b0, w1, c0, w2);
            float c3y = wsum3(a1, w0, b1, w1, c1, w2);
            float c3z = wsum3(a2, w0, b2, w1, c2, w2);
            float e1x = b0 - a0, e1y = b1 - a1, e1z = b2 - a2;
            float e2x = c0 - a0, e2y = c1 - a1, e2z = c2 - a2;
            float nx = e1y * e2z - e1z * e2y;
            float ny = e1z * e2x - e1x * e2z;
            float nz = e1x * e2y - e1y * e2x;
            float nn = sqrtf(nx * nx + ny * ny + nz * nz) + 1e-8f;
            nx /= nn; ny /= nn; nz /= nn;
            float vn = sqrtf(c3x * c3x + c3y * c3y + c3z * c3z) + 1e-8f;
            float vx = -c3x / vn, vy = -c3y / vn, vz = -c3z / vn;
            float ang = fmaxf(nx * vx + ny * vy + nz * vz, 0.0f);
            int xc = (int)rintf(c2x); xc = min(max(xc, 0), W - 1);
            int yc = (int)rintf(c2y); yc = min(max(yc, 0), H - 1);
            float dsamp = dep[(size_t)yc * W + xc];
            bool visible = (c3z <= dsamp + 1e-3f) || isinf(dsamp);
            out_vw[idx] = visible ? ang : 0.0f;
            out_c3[(size_t)idx * 3 + 0] = c3x;
            out_c3[(size_t)idx * 3 + 1] = c3y;
            out_c3[(size_t)idx * 3 + 2] = c3z;
            float px = to_pix(c2x, W - 1, WF - 1);
            float py = to_pix(c2y, H - 1, HF - 1);
            float x0f = floorf(px), y0f = floorf(py);
            int x0i = (int)x0f, y0i = (int)y0f;
            float wx = px - x0f, wy = py - y0f;
            unsigned int xs = (unsigned int)min(max(x0i + 8, 0), 65535);
            unsigned int ys = (unsigned int)min(max(y0i + 8, 0), 65535);
            unsigned short hx = __half_as_ushort(__float2half(wx));
            unsigned short hy = __half_as_ushort(__float2half(wy));
            u2 rec;
            rec.x = (ys << 16) | xs;
            rec.y = ((unsigned int)hy << 16) | hx;
            sp[tid] = rec;
        }
        __syncthreads();
        // ---- phase 2: gather 256 points, 8 slots x 32 lanes ----
        for (int i = slot; i < cnt; i += 8) {
            u2 rec = sp[i];   // slot-uniform -> LDS broadcast
            int n = t0 + i;
            int x0 = (int)(rec.x & 0xffff) - 8;
            int y0 = (int)(rec.x >> 16) - 8;
            float wx = __half2float(__ushort_as_half((unsigned short)(rec.y & 0xffff)));
            float wy = __half2float(__ushort_as_half((unsigned short)(rec.y >> 16)));
            // clamped indices + zeroed weights (matches reference clip + w*ok exactly)
            int xA = min(max(x0, 0), WF - 1), xB = min(max(x0 + 1, 0), WF - 1);
            int yA = min(max(y0, 0), HF - 1), yB = min(max(y0 + 1, 0), HF - 1);
            float okxA = (x0 >= 0 && x0 < WF) ? 1.0f : 0.0f;
            float okxB = (x0 + 1 >= 0 && x0 + 1 < WF) ? 1.0f : 0.0f;
            float okyA = (y0 >= 0 && y0 < HF) ? 1.0f : 0.0f;
            float okyB = (y0 + 1 >= 0 && y0 + 1 < HF) ? 1.0f : 0.0f;
            float w00 = (1.0f - wx) * (1.0f - wy) * okxA * okyA;
            float w10 = wx * (1.0f - wy) * okxB * okyA;
            float w01 = (1.0f - wx) * wy * okxA * okyB;
            float w11 = wx * wy * okxB * okyB;
            const u2* q00 = (const u2*)(base + ((size_t)yA * WF + xA) * CC + co);
            const u2* q10 = (const u2*)(base + ((size_t)yA * WF + xB) * CC + co);
            const u2* q01 = (const u2*)(base + ((size_t)yB * WF + xA) * CC + co);
            const u2* q11 = (const u2*)(base + ((size_t)yB * WF + xB) * CC + co);
            u2 r00 = *q00, r10 = *q10, r01 = *q01, r11 = *q11;
#define BF16X4(r, v)                                                \
            f4 v;                                                   \
            v.x = __uint_as_float((r.x & 0xffffu) << 16);           \
            v.y = __uint_as_float(r.x & 0xffff0000u);               \
            v.z = __uint_as_float((r.y & 0xffffu) << 16);           \
            v.w = __uint_as_float(r.y & 0xffff0000u);
            BF16X4(r00, v00); BF16X4(r10, v10); BF16X4(r01, v01); BF16X4(r11, v11);
#undef BF16X4
            f4 acc = v00 * w00 + v10 * w10 + v01 * w01 + v11 * w11;
            __builtin_nontemporal_store(acc, obase + (size_t)n * (CC / 4) + lane);
        }
        __syncthreads();
    }
}

extern "C" void kernel_launch(void* const* d_in, const int* in_sizes, int n_in,
                              void* d_out, int out_size, void* d_ws, size_t ws_size,
                              hipStream_t stream) {
    const float* fm = (const float*)d_in[0];
    const float* v2d = (const float*)d_in[1];
    const float* v3d = (const float*)d_in[2];
    const int* parents = (const int*)d_in[3];
    const float* bary = (const float*)d_in[4];
    const int* pH = (const int*)d_in[5];
    const int* pW = (const int*)d_in[6];

    int Nv = in_sizes[1] / (BB * 2);
    int N = in_sizes[3] / 3;
    int K = in_sizes[4] / 3;

    // workspace layout: fmT bf16 (16.8MB) | depth (4MB)
    unsigned short* fmT = (unsigned short*)d_ws;
    float* depth = (float*)(fmT + (size_t)BB * HF * WF * CC);

    float* out_lf = (float*)d_out;
    float* out_vw = out_lf + (size_t)BB * N * CC;
    float* out_c3 = out_vw + (size_t)BB * N;

    hipLaunchKernelGGL(transpose_fm, dim3(HF * WF / 32, CC / 32, BB), dim3(32, 8), 0, stream,
                       fm, fmT, depth);
    hipLaunchKernelGGL(depth_scatter, dim3((BB * Nv + 255) / 256), dim3(256), 0, stream,
                       v2d, v3d, depth, Nv, pH, pW);
    hipLaunchKernelGGL(gather_fused, dim3(GATHER_NB), dim3(256), 0, stream,
                       fmT, v2d, v3d, parents, bary, depth, out_vw, out_c3, out_lf,
                       N, Nv, K, pH, pW);
}